// Round 1
// baseline (44.260 us; speedup 1.0000x reference)
//
#include <hip/hip_runtime.h>

#define NB 2048   // rows (B)
#define NC 8192   // classes (C)
#define NP 8      // positives per row (P)
#define BLK 256

__global__ __launch_bounds__(BLK) void mlce_row_kernel(
    const float* __restrict__ pred,
    const int* __restrict__ labels,
    double* __restrict__ acc) {
    const int row = blockIdx.x;
    const int tid = threadIdx.x;
    const float4* rowp = reinterpret_cast<const float4*>(pred + (size_t)row * NC);

    // One pass: sum of exp over the full row, vectorized float4.
    float partial = 0.f;
#pragma unroll
    for (int i = 0; i < NC / 4 / BLK; ++i) {
        float4 v = rowp[tid + i * BLK];
        partial += __expf(v.x) + __expf(v.y) + __expf(v.z) + __expf(v.w);
    }

    // Wave-64 shuffle reduce.
#pragma unroll
    for (int off = 32; off > 0; off >>= 1)
        partial += __shfl_down(partial, off, 64);

    __shared__ float wsum[BLK / 64];
    __shared__ float plog[NP];
    const int lane = tid & 63;
    const int wid = tid >> 6;
    if (lane == 0) wsum[wid] = partial;
    if (tid < NP) {
        int lab = labels[row * NP + tid];
        plog[tid] = pred[(size_t)row * NC + lab];
    }
    __syncthreads();

    if (tid == 0) {
        float s_all = 0.f;
#pragma unroll
        for (int w = 0; w < BLK / 64; ++w) s_all += wsum[w];
        float pe[NP];
        float s_pos = 0.f;
#pragma unroll
        for (int p = 0; p < NP; ++p) { pe[p] = __expf(plog[p]); s_pos += pe[p]; }
        const float s_neg = s_all - s_pos;
        float loss = 0.f;
#pragma unroll
        for (int p = 0; p < NP; ++p) loss += __logf(s_neg + pe[p]) - plog[p];
        atomicAdd(acc, (double)loss);
    }
}

__global__ void mlce_finalize_kernel(const double* __restrict__ acc,
                                     float* __restrict__ out) {
    out[0] = (float)(acc[0] / (double)(NB * NP));
}

extern "C" void kernel_launch(void* const* d_in, const int* in_sizes, int n_in,
                              void* d_out, int out_size, void* d_ws, size_t ws_size,
                              hipStream_t stream) {
    const float* pred = (const float*)d_in[0];
    const int* labels = (const int*)d_in[1];
    float* out = (float*)d_out;
    double* acc = (double*)d_ws;

    // Zero the accumulator every call (harness does not re-poison between replays).
    hipMemsetAsync(acc, 0, sizeof(double), stream);

    mlce_row_kernel<<<NB, BLK, 0, stream>>>(pred, labels, acc);
    mlce_finalize_kernel<<<1, 1, 0, stream>>>(acc, out);
}

// Round 2
// 18.097 us; speedup vs baseline: 2.4457x; 2.4457x over previous
//
#include <hip/hip_runtime.h>

#define NB 2048   // rows (B)
#define NC 8192   // classes (C)
#define NP 8      // positives per row (P)
#define BLK 256

// Stage 1: one block per row. Sum exp over the row, then thread 0 computes
// the row's multi-label CE contribution and writes it to row_loss[row].
__global__ __launch_bounds__(BLK) void mlce_row_kernel(
    const float* __restrict__ pred,
    const int* __restrict__ labels,
    float* __restrict__ row_loss) {
    const int row = blockIdx.x;
    const int tid = threadIdx.x;
    const float4* rowp = reinterpret_cast<const float4*>(pred + (size_t)row * NC);

    // Independent accumulators to shorten the add chain; loads fully unrolled
    // so all 8 float4 loads are in flight before the first use.
    float a0 = 0.f, a1 = 0.f, a2 = 0.f, a3 = 0.f;
    float4 v[NC / 4 / BLK];
#pragma unroll
    for (int i = 0; i < NC / 4 / BLK; ++i) v[i] = rowp[tid + i * BLK];
#pragma unroll
    for (int i = 0; i < NC / 4 / BLK; ++i) {
        a0 += __expf(v[i].x);
        a1 += __expf(v[i].y);
        a2 += __expf(v[i].z);
        a3 += __expf(v[i].w);
    }
    float partial = (a0 + a1) + (a2 + a3);

    // Wave-64 shuffle reduce.
#pragma unroll
    for (int off = 32; off > 0; off >>= 1)
        partial += __shfl_down(partial, off, 64);

    __shared__ float wsum[BLK / 64];
    __shared__ float plog[NP];
    const int lane = tid & 63;
    const int wid = tid >> 6;
    if (lane == 0) wsum[wid] = partial;
    if (tid < NP) {
        int lab = labels[row * NP + tid];
        plog[tid] = pred[(size_t)row * NC + lab];
    }
    __syncthreads();

    if (tid == 0) {
        float s_all = 0.f;
#pragma unroll
        for (int w = 0; w < BLK / 64; ++w) s_all += wsum[w];
        float pe[NP];
        float s_pos = 0.f;
#pragma unroll
        for (int p = 0; p < NP; ++p) { pe[p] = __expf(plog[p]); s_pos += pe[p]; }
        const float s_neg = s_all - s_pos;
        float loss = 0.f;
#pragma unroll
        for (int p = 0; p < NP; ++p) loss += __logf(s_neg + pe[p]) - plog[p];
        row_loss[row] = loss;
    }
}

// Stage 2: single block reduces the 2048 per-row losses to the mean.
__global__ __launch_bounds__(BLK) void mlce_reduce_kernel(
    const float* __restrict__ row_loss,
    float* __restrict__ out) {
    const int tid = threadIdx.x;
    float s = 0.f;
#pragma unroll
    for (int i = 0; i < NB / BLK; ++i) s += row_loss[tid + i * BLK];
#pragma unroll
    for (int off = 32; off > 0; off >>= 1)
        s += __shfl_down(s, off, 64);

    __shared__ float wsum[BLK / 64];
    const int lane = tid & 63;
    const int wid = tid >> 6;
    if (lane == 0) wsum[wid] = s;
    __syncthreads();
    if (tid == 0) {
        float tot = 0.f;
#pragma unroll
        for (int w = 0; w < BLK / 64; ++w) tot += wsum[w];
        out[0] = tot / (float)(NB * NP);
    }
}

extern "C" void kernel_launch(void* const* d_in, const int* in_sizes, int n_in,
                              void* d_out, int out_size, void* d_ws, size_t ws_size,
                              hipStream_t stream) {
    const float* pred = (const float*)d_in[0];
    const int* labels = (const int*)d_in[1];
    float* out = (float*)d_out;
    float* row_loss = (float*)d_ws;   // NB floats; every slot written each call

    mlce_row_kernel<<<NB, BLK, 0, stream>>>(pred, labels, row_loss);
    mlce_reduce_kernel<<<1, BLK, 0, stream>>>(row_loss, out);
}